// Round 16
// baseline (2933.341 us; speedup 1.0000x reference)
//
#include <hip/hip_runtime.h>

#define B_ 256
#define T_ 80
#define IN_ 39
#define H_ 256
#define G_ 1024
#define L_ 5
#define TC_ 16
#define NCH_ 5

#define XP_FLOATS   (B_ * TC_ * G_)     // 4,194,304
#define HBUF_FLOATS (B_ * T_ * H_)      // 5,242,880
#define CBUF_FLOATS (B_ * H_)           // 65,536
#define WG_FLOATS   (L_ * G_ * H_)      // 1,310,720
#define HX_FLOATS   (2 * 32 * 2048)     // 131,072
#define FLG_OFF_FLOATS (XP_FLOATS + HBUF_FLOATS + CBUF_FLOATS + WG_FLOATS + HX_FLOATS)

#define AG __HIP_MEMORY_SCOPE_AGENT

__device__ __forceinline__ float sigm(float x) { return 1.0f / (1.0f + expf(-x)); }
__device__ __forceinline__ void fma4(float4& a, float s, const float4& w) {
    a.x = fmaf(s, w.x, a.x); a.y = fmaf(s, w.y, a.y);
    a.z = fmaf(s, w.z, a.z); a.w = fmaf(s, w.w, a.w);
}
__device__ __forceinline__ void red4(float4& a) {
    a.x += __shfl_xor(a.x, 32); a.y += __shfl_xor(a.y, 32);
    a.z += __shfl_xor(a.z, 32); a.w += __shfl_xor(a.w, 32);
}

// MALL-coherent 16B load (sc0+sc1, the cache-op bits of agent-scope atomics).
__device__ __forceinline__ float4 ld_mall_16B(const float* p) {
    float4 v;
    asm volatile("global_load_dwordx4 %0, %1, off sc0 sc1\n\t"
                 "s_waitcnt vmcnt(0)"
                 : "=&v"(v) : "v"(p) : "memory");
    return v;
}

// ---- Wg: per-slice interleaved W_hh: Wg[l][s][k][j][g] = Whh[l][g*256+s*32+j][k] ----
extern "C" __global__ void __launch_bounds__(256)
wt_kernel(const float* __restrict__ Whh, float* __restrict__ Wg) {
    const int gid = blockIdx.x * 256 + threadIdx.x;
    const int g4 = gid & 3;
    const int j  = (gid >> 2) & 31;
    const int k  = (gid >> 7) & 255;
    const int s  = (gid >> 15) & 7;
    const int l  = gid >> 18;
    Wg[gid] = Whh[((size_t)(l * 1024 + g4 * 256 + s * 32 + j)) * 256 + k];
}

// ---- projection GEMM; xp GATE-PACKED xp[row][unit][gate] (r15, proven) ----
extern "C" __global__ void __launch_bounds__(256)
proj_kernel(const float* __restrict__ src, const float* __restrict__ Wih,
            const float* __restrict__ bihl, const float* __restrict__ bhhl,
            float* __restrict__ xp, int K, int t0) {
    __shared__ float As[16 * 68];
    __shared__ float Bs[16 * 68];
    const int tid = threadIdx.x;
    const int mt = blockIdx.x >> 4, nt = blockIdx.x & 15;
    const int tx = tid & 15, ty = tid >> 4;
    const int lr = tid >> 2, lc4 = (tid & 3) << 2;

    const int ar = mt * 64 + lr;
    const int ab = ar >> 4;
    const int at = t0 + (ar & 15);
    const float* arow = src + ((size_t)ab * T_ + at) * K;
    const int brow_idx = (lr & 3) * 256 + nt * 16 + (lr >> 2);   // permuted W row
    const float* brow = Wih + (size_t)brow_idx * K;

    float acc[4][4];
    #pragma unroll
    for (int i = 0; i < 4; ++i)
        #pragma unroll
        for (int j = 0; j < 4; ++j) acc[i][j] = 0.0f;

    for (int k0 = 0; k0 < K; k0 += 16) {
        __syncthreads();
        if (K == IN_) {
            #pragma unroll
            for (int i = 0; i < 4; ++i) {
                int k = k0 + lc4 + i;
                As[(lc4 + i) * 68 + lr] = (k < IN_) ? arow[k] : 0.0f;
                Bs[(lc4 + i) * 68 + lr] = (k < IN_) ? brow[k] : 0.0f;
            }
        } else {
            float4 av = *(const float4*)(arow + k0 + lc4);
            float4 bv = *(const float4*)(brow + k0 + lc4);
            As[(lc4 + 0) * 68 + lr] = av.x;
            As[(lc4 + 1) * 68 + lr] = av.y;
            As[(lc4 + 2) * 68 + lr] = av.z;
            As[(lc4 + 3) * 68 + lr] = av.w;
            Bs[(lc4 + 0) * 68 + lr] = bv.x;
            Bs[(lc4 + 1) * 68 + lr] = bv.y;
            Bs[(lc4 + 2) * 68 + lr] = bv.z;
            Bs[(lc4 + 3) * 68 + lr] = bv.w;
        }
        __syncthreads();
        #pragma unroll
        for (int kk = 0; kk < 16; ++kk) {
            float4 a4 = *(const float4*)&As[kk * 68 + ty * 4];
            float4 b4 = *(const float4*)&Bs[kk * 68 + tx * 4];
            acc[0][0] += a4.x * b4.x; acc[0][1] += a4.x * b4.y;
            acc[0][2] += a4.x * b4.z; acc[0][3] += a4.x * b4.w;
            acc[1][0] += a4.y * b4.x; acc[1][1] += a4.y * b4.y;
            acc[1][2] += a4.y * b4.z; acc[1][3] += a4.y * b4.w;
            acc[2][0] += a4.z * b4.x; acc[2][1] += a4.z * b4.y;
            acc[2][2] += a4.z * b4.z; acc[2][3] += a4.z * b4.w;
            acc[3][0] += a4.w * b4.x; acc[3][1] += a4.w * b4.y;
            acc[3][2] += a4.w * b4.z; acc[3][3] += a4.w * b4.w;
        }
    }
    const int unit = nt * 16 + tx;
    const float bs0 = bihl[0 * 256 + unit] + bhhl[0 * 256 + unit];
    const float bs1 = bihl[1 * 256 + unit] + bhhl[1 * 256 + unit];
    const float bs2 = bihl[2 * 256 + unit] + bhhl[2 * 256 + unit];
    const float bs3 = bihl[3 * 256 + unit] + bhhl[3 * 256 + unit];
    #pragma unroll
    for (int i = 0; i < 4; ++i) {
        const int row = mt * 64 + ty * 4 + i;
        float4 o;
        o.x = acc[i][0] + bs0; o.y = acc[i][1] + bs1;
        o.z = acc[i][2] + bs2; o.w = acc[i][3] + bs3;
        *(float4*)&xp[(size_t)row * G_ + unit * 4] = o;   // coalesced, gate-packed
    }
}

// ---- recurrence: 2-COHORT pipelined exchange (A = fb 0-3, B = fb 4-7) ----
// Per step: half-step A then half-step B, each with its own flag line. While
// cohort A's publish+flag propagates through MALL, the block computes cohort
// B -> the hop latency hides under compute. Flag discipline identical to r15
// (relaxed stores, vmcnt(0) drain + barrier before flag; monotonic targets;
// same program order in all blocks -> deadlock-free). hbuf writes deferred to
// end-of-chunk via LDS history (shorter per-step drain).
extern "C" __global__ void __launch_bounds__(512, 2)
rec9_kernel(const float* __restrict__ xp, const float* __restrict__ Wg_l,
            float* __restrict__ hbuf, float* __restrict__ cbuf,
            float* __restrict__ hx, int* __restrict__ flg,
            int t0, int chkb, int first) {
    __shared__ float sH[2048];          // hT[k][fb]  (8 KB)
    __shared__ float sP[8 * 32 * 36];   // part[w][jj][36] (36 KB)
    __shared__ float sHist[8 * 32 * 16];// h history [fbb][fj][tt] (16 KB)

    const int tid = threadIdx.x;
    const int bid = blockIdx.x;
    const int grp = bid & 31;
    const int s   = bid >> 5;
    const int jj  = tid & 31;       // main identity: unit
    const int ks  = tid >> 5;       // main identity: k-slice (0..15)
    const int w   = tid >> 6;       // wave id (0..7)
    const int fbb = (tid >> 5) & 7; // finish identity: batch 0..7 (tid<256)
    const int fj  = tid & 31;       // finish identity: unit
    const int bglob = grp * 8 + fbb;
    const int unit  = s * 32 + fj;

    // W fragment into registers
    const float4* Wg4 = (const float4*)Wg_l + (size_t)s * 8192;
    float4 wreg[16];
    #pragma unroll
    for (int kk = 0; kk < 16; ++kk)
        wreg[kk] = Wg4[(size_t)(ks * 16 + kk) * 32 + jj];

    float creg = 0.0f;
    if (tid < 256 && !first) creg = cbuf[(size_t)bglob * H_ + unit];

    const float4* sH4 = (const float4*)sH;

    for (int tt = 0; tt < TC_; ++tt) {
        // xp prefetch for both cohorts (tid<256), gate-packed float4
        float x0 = 0.f, x1 = 0.f, x2 = 0.f, x3 = 0.f;
        if (tid < 256) {
            const float4 xv = *(const float4*)&xp[((size_t)bglob * TC_ + tt) * G_ + unit * 4];
            x0 = xv.x; x1 = xv.y; x2 = xv.z; x3 = xv.w;
        }

        #pragma unroll
        for (int c = 0; c < 2; ++c) {
            // ---- poll cohort-c flags (or initial hbuf gather at tt==0) ----
            if (tt == 0) {
                if (c == 0) {
                    if (first) {
                        for (int i = tid; i < 2048; i += 512) sH[i] = 0.0f;
                    } else if (tid < 256) {
                        #pragma unroll
                        for (int bb = 0; bb < 8; ++bb)
                            sH[tid * 8 + bb] =
                                hbuf[((size_t)(grp * 8 + bb) * T_ + (t0 - 1)) * H_ + tid];
                    }
                }
            } else {
                if (tid < 8) {
                    int* fp = flg + (grp * 2 + c) * 32 + tid;
                    const int tgt = chkb + tt;
                    while (__hip_atomic_load(fp, __ATOMIC_RELAXED, AG) < tgt)
                        __builtin_amdgcn_s_sleep(1);
                }
            }
            __syncthreads();

            // ---- gather cohort-c h(t-1): one 16B MALL load per unit ----
            if (tt > 0 && tid < 256) {
                const float* hsf = hx + (size_t)(((tt - 1) & 1) * 32 + grp) * 2048
                                      + (size_t)tid * 8 + c * 4;
                *(float4*)&sH[tid * 8 + c * 4] = ld_mall_16B(hsf);
            }
            __syncthreads();  // sH cohort-c ready

            // ---- phase B: cohort-c k-loop (4 accumulators) ----
            float4 a0 = {0,0,0,0}, a1 = {0,0,0,0}, a2 = {0,0,0,0}, a3 = {0,0,0,0};
            #pragma unroll
            for (int kk = 0; kk < 16; ++kk) {
                const int k = ks * 16 + kk;
                const float4 wv = wreg[kk];
                const float4 hc = sH4[k * 2 + c];
                fma4(a0, hc.x, wv); fma4(a1, hc.y, wv);
                fma4(a2, hc.z, wv); fma4(a3, hc.w, wv);
            }
            red4(a0); red4(a1); red4(a2); red4(a3);
            if ((tid & 63) < 32) {
                float4* pp = (float4*)&sP[(w * 32 + jj) * 36];
                pp[0] = a0; pp[1] = a1; pp[2] = a2; pp[3] = a3;
            }
            __syncthreads();  // partials ready

            // ---- phase C: finish cohort c (threads tid>>7 == c, tid<256) ----
            if (tid < 256 && (tid >> 7) == c) {
                const int fb2 = fbb & 3;
                float4 g4;
                g4.x = x0; g4.y = x1; g4.z = x2; g4.w = x3;
                #pragma unroll
                for (int w2 = 0; w2 < 8; ++w2) {
                    const float4 pw = *(const float4*)&sP[(w2 * 32 + fj) * 36 + fb2 * 4];
                    g4.x += pw.x; g4.y += pw.y; g4.z += pw.z; g4.w += pw.w;
                }
                const float I = sigm(g4.x);
                const float F = sigm(g4.y);
                const float Gt = tanhf(g4.z);
                const float O = sigm(g4.w);
                creg = F * creg + I * Gt;
                const float hval = O * tanhf(creg);
                sHist[(fbb * 32 + fj) * 16 + tt] = hval;   // deferred hbuf

                if (tt < TC_ - 1) {
                    // paired publish: fb2 even lane packs (fb2, fb2^1) into u64
                    const float hpart = __shfl_xor(hval, 32);
                    if ((fb2 & 1) == 0) {
                        const unsigned long long pv =
                            ((unsigned long long)__float_as_uint(hpart) << 32)
                            | __float_as_uint(hval);
                        unsigned long long* dst = (unsigned long long*)
                            (hx + (size_t)((tt & 1) * 32 + grp) * 2048
                                + unit * 8 + c * 4 + fb2);
                        __hip_atomic_store(dst, pv, __ATOMIC_RELAXED, AG);
                    }
                }
            }

            if (tt < TC_ - 1) {
                asm volatile("s_waitcnt vmcnt(0)" ::: "memory");
                __syncthreads();  // publishes drained; sP free
                if (tid == 0)
                    __hip_atomic_store(flg + (grp * 2 + c) * 32 + s, chkb + tt + 1,
                                       __ATOMIC_RELAXED, AG);
            } else {
                __syncthreads();  // protect sP before next half / writeback
            }
        }
    }

    // ---- end of chunk: write h history + cell state ----
    if (tid < 256) {
        #pragma unroll
        for (int tt = 0; tt < TC_; ++tt)
            hbuf[((size_t)bglob * T_ + (t0 + tt)) * H_ + unit] =
                sHist[(fbb * 32 + fj) * 16 + tt];
        cbuf[(size_t)bglob * H_ + unit] = creg;
    }
}

// ---- final FC ----
extern "C" __global__ void __launch_bounds__(128)
fc_kernel(const float* __restrict__ hbuf, const float* __restrict__ fcw,
          const float* __restrict__ fcb, float* __restrict__ out) {
    __shared__ float wsm[256];
    const int tid = threadIdx.x;
    const int b = blockIdx.x;
    if (tid < 64) ((float4*)wsm)[tid] = ((const float4*)fcw)[tid];
    __syncthreads();
    if (tid < T_) {
        const float4* h4p = (const float4*)(hbuf + ((size_t)b * T_ + tid) * H_);
        const float4* w4p = (const float4*)wsm;
        float acc = fcb[0];
        #pragma unroll 8
        for (int k4 = 0; k4 < 64; ++k4) {
            float4 h4 = h4p[k4], w4 = w4p[k4];
            acc += h4.x * w4.x + h4.y * w4.y + h4.z * w4.z + h4.w * w4.w;
        }
        out[b * T_ + tid] = acc;
    }
}

extern "C" void kernel_launch(void* const* d_in, const int* in_sizes, int n_in,
                              void* d_out, int out_size, void* d_ws, size_t ws_size,
                              hipStream_t stream) {
    (void)in_sizes; (void)n_in; (void)out_size; (void)ws_size;
    const float* x    = (const float*)d_in[0];
    const float* Wih0 = (const float*)d_in[1];
    const float* Wihr = (const float*)d_in[2];
    const float* Whh  = (const float*)d_in[3];
    const float* bih  = (const float*)d_in[4];
    const float* bhh  = (const float*)d_in[5];
    const float* fcw  = (const float*)d_in[6];
    const float* fcb  = (const float*)d_in[7];
    float* out = (float*)d_out;
    float* ws  = (float*)d_ws;

    float* xp   = ws;
    float* hbuf = ws + XP_FLOATS;
    float* cbuf = hbuf + HBUF_FLOATS;
    float* wg   = cbuf + CBUF_FLOATS;
    float* hx   = wg + WG_FLOATS;
    int*   flg  = (int*)(ws + FLG_OFF_FLOATS);   // 64 lines x 32 ints

    hipMemsetAsync(flg, 0, 64 * 32 * sizeof(int), stream);
    hipLaunchKernelGGL(wt_kernel, dim3(WG_FLOATS / 256), dim3(256), 0, stream, Whh, wg);

    for (int l = 0; l < L_; ++l) {
        const int K = (l == 0) ? IN_ : H_;
        const float* src = (l == 0) ? x : hbuf;
        const float* Wih = (l == 0) ? Wih0 : (Wihr + (size_t)(l - 1) * G_ * H_);
        const float* Wg_l = wg + (size_t)l * (G_ * H_);
        for (int ch = 0; ch < NCH_; ++ch) {
            const int t0 = ch * TC_;
            const int chkb = (l * NCH_ + ch) * (TC_ - 1);
            hipLaunchKernelGGL(proj_kernel, dim3(1024), dim3(256), 0, stream,
                               src, Wih, bih + l * G_, bhh + l * G_, xp, K, t0);
            hipLaunchKernelGGL(rec9_kernel, dim3(256), dim3(512), 0, stream,
                               xp, Wg_l, hbuf, cbuf, hx, flg, t0, chkb, ch == 0 ? 1 : 0);
        }
    }
    hipLaunchKernelGGL(fc_kernel, dim3(B_), dim3(128), 0, stream, hbuf, fcw, fcb, out);
}

// Round 17
// 2479.565 us; speedup vs baseline: 1.1830x; 1.1830x over previous
//
#include <hip/hip_runtime.h>

#define B_ 256
#define T_ 80
#define IN_ 39
#define H_ 256
#define G_ 1024
#define L_ 5
#define TC_ 16
#define NCH_ 5

#define XP_FLOATS   (B_ * TC_ * G_)     // 4,194,304
#define HBUF_FLOATS (B_ * T_ * H_)      // 5,242,880
#define CBUF_FLOATS (B_ * H_)           // 65,536
#define WG_FLOATS   (L_ * G_ * H_)      // 1,310,720
#define HX_FLOATS   (2 * 32 * 2048)     // 131,072
#define FLG_OFF_FLOATS (XP_FLOATS + HBUF_FLOATS + CBUF_FLOATS + WG_FLOATS + HX_FLOATS)

#define AG __HIP_MEMORY_SCOPE_AGENT
#define WG __HIP_MEMORY_SCOPE_WORKGROUP

__device__ __forceinline__ float sigm(float x) { return 1.0f / (1.0f + expf(-x)); }
__device__ __forceinline__ void fma4(float4& a, float s, const float4& w) {
    a.x = fmaf(s, w.x, a.x); a.y = fmaf(s, w.y, a.y);
    a.z = fmaf(s, w.z, a.z); a.w = fmaf(s, w.w, a.w);
}
__device__ __forceinline__ void red4(float4& a) {
    a.x += __shfl_xor(a.x, 32); a.y += __shfl_xor(a.y, 32);
    a.z += __shfl_xor(a.z, 32); a.w += __shfl_xor(a.w, 32);
}

// MALL-coherent 16B load (sc0+sc1 = agent-atomic cache bits, 16B wide; r14+).
__device__ __forceinline__ float4 ld_mall_16B(const float* p) {
    float4 v;
    asm volatile("global_load_dwordx4 %0, %1, off sc0 sc1\n\t"
                 "s_waitcnt vmcnt(0)"
                 : "=&v"(v) : "v"(p) : "memory");
    return v;
}

// 4-wave cohort barrier: monotonic LDS counter (ds_add by lane 0 of each
// wave + all-lane broadcast spin). lgkmcnt(0) fences DS ops on both sides.
__device__ __forceinline__ void cbar(int* cnt, int& seq) {
    seq += 4;
    asm volatile("s_waitcnt lgkmcnt(0)" ::: "memory");
    if ((threadIdx.x & 63) == 0)
        __hip_atomic_fetch_add(cnt, 1, __ATOMIC_RELAXED, WG);
    while (__hip_atomic_load(cnt, __ATOMIC_RELAXED, WG) < seq)
        __builtin_amdgcn_s_sleep(1);
    asm volatile("s_waitcnt lgkmcnt(0)" ::: "memory");
}

// ---- Wg: per-slice interleaved W_hh: Wg[l][s][k][j][g] = Whh[l][g*256+s*32+j][k] ----
extern "C" __global__ void __launch_bounds__(256)
wt_kernel(const float* __restrict__ Whh, float* __restrict__ Wg) {
    const int gid = blockIdx.x * 256 + threadIdx.x;
    const int g4 = gid & 3;
    const int j  = (gid >> 2) & 31;
    const int k  = (gid >> 7) & 255;
    const int s  = (gid >> 15) & 7;
    const int l  = gid >> 18;
    Wg[gid] = Whh[((size_t)(l * 1024 + g4 * 256 + s * 32 + j)) * 256 + k];
}

// ---- projection GEMM; xp GATE-PACKED xp[row][unit][gate] (r15, proven) ----
extern "C" __global__ void __launch_bounds__(256)
proj_kernel(const float* __restrict__ src, const float* __restrict__ Wih,
            const float* __restrict__ bihl, const float* __restrict__ bhhl,
            float* __restrict__ xp, int K, int t0) {
    __shared__ float As[16 * 68];
    __shared__ float Bs[16 * 68];
    const int tid = threadIdx.x;
    const int mt = blockIdx.x >> 4, nt = blockIdx.x & 15;
    const int tx = tid & 15, ty = tid >> 4;
    const int lr = tid >> 2, lc4 = (tid & 3) << 2;

    const int ar = mt * 64 + lr;
    const int ab = ar >> 4;
    const int at = t0 + (ar & 15);
    const float* arow = src + ((size_t)ab * T_ + at) * K;
    const int brow_idx = (lr & 3) * 256 + nt * 16 + (lr >> 2);   // permuted W row
    const float* brow = Wih + (size_t)brow_idx * K;

    float acc[4][4];
    #pragma unroll
    for (int i = 0; i < 4; ++i)
        #pragma unroll
        for (int j = 0; j < 4; ++j) acc[i][j] = 0.0f;

    for (int k0 = 0; k0 < K; k0 += 16) {
        __syncthreads();
        if (K == IN_) {
            #pragma unroll
            for (int i = 0; i < 4; ++i) {
                int k = k0 + lc4 + i;
                As[(lc4 + i) * 68 + lr] = (k < IN_) ? arow[k] : 0.0f;
                Bs[(lc4 + i) * 68 + lr] = (k < IN_) ? brow[k] : 0.0f;
            }
        } else {
            float4 av = *(const float4*)(arow + k0 + lc4);
            float4 bv = *(const float4*)(brow + k0 + lc4);
            As[(lc4 + 0) * 68 + lr] = av.x;
            As[(lc4 + 1) * 68 + lr] = av.y;
            As[(lc4 + 2) * 68 + lr] = av.z;
            As[(lc4 + 3) * 68 + lr] = av.w;
            Bs[(lc4 + 0) * 68 + lr] = bv.x;
            Bs[(lc4 + 1) * 68 + lr] = bv.y;
            Bs[(lc4 + 2) * 68 + lr] = bv.z;
            Bs[(lc4 + 3) * 68 + lr] = bv.w;
        }
        __syncthreads();
        #pragma unroll
        for (int kk = 0; kk < 16; ++kk) {
            float4 a4 = *(const float4*)&As[kk * 68 + ty * 4];
            float4 b4 = *(const float4*)&Bs[kk * 68 + tx * 4];
            acc[0][0] += a4.x * b4.x; acc[0][1] += a4.x * b4.y;
            acc[0][2] += a4.x * b4.z; acc[0][3] += a4.x * b4.w;
            acc[1][0] += a4.y * b4.x; acc[1][1] += a4.y * b4.y;
            acc[1][2] += a4.y * b4.z; acc[1][3] += a4.y * b4.w;
            acc[2][0] += a4.z * b4.x; acc[2][1] += a4.z * b4.y;
            acc[2][2] += a4.z * b4.z; acc[2][3] += a4.z * b4.w;
            acc[3][0] += a4.w * b4.x; acc[3][1] += a4.w * b4.y;
            acc[3][2] += a4.w * b4.z; acc[3][3] += a4.w * b4.w;
        }
    }
    const int unit = nt * 16 + tx;
    const float bs0 = bihl[0 * 256 + unit] + bhhl[0 * 256 + unit];
    const float bs1 = bihl[1 * 256 + unit] + bhhl[1 * 256 + unit];
    const float bs2 = bihl[2 * 256 + unit] + bhhl[2 * 256 + unit];
    const float bs3 = bihl[3 * 256 + unit] + bhhl[3 * 256 + unit];
    #pragma unroll
    for (int i = 0; i < 4; ++i) {
        const int row = mt * 64 + ty * 4 + i;
        float4 o;
        o.x = acc[i][0] + bs0; o.y = acc[i][1] + bs1;
        o.z = acc[i][2] + bs2; o.w = acc[i][3] + bs3;
        *(float4*)&xp[(size_t)row * G_ + unit * 4] = o;   // coalesced, gate-packed
    }
}

// ---- recurrence: CONCURRENT cohorts (waves 0-3 = batches 0-3, waves 4-7 =
// batches 4-7). No __syncthreads in the loop; each cohort uses its own 4-wave
// LDS barrier, flag line, sH half, sP region. While one cohort sleeps on its
// MALL hop, the other cohort's waves compute on the same SIMDs.
extern "C" __global__ void __launch_bounds__(512, 2)
rec10_kernel(const float* __restrict__ xp, const float* __restrict__ Wg_l,
             float* __restrict__ hbuf, float* __restrict__ cbuf,
             float* __restrict__ hx, int* __restrict__ flg,
             int t0, int chkb, int first) {
    __shared__ float sH[2048];              // hT[k][fb] (8 KB), cohort halves
    __shared__ float sP[2 * 4 * 32 * 20];   // per-cohort part[w4][jj][20]
    __shared__ int   barC[2];

    const int tid = threadIdx.x;
    const int bid = blockIdx.x;
    const int grp = bid & 31;
    const int s   = bid >> 5;
    const int c   = tid >> 8;       // cohort 0/1
    const int tp  = tid & 255;      // index within cohort
    const int jj  = tp & 31;        // unit within slice
    const int ks  = tp >> 5;        // k-slice (0..7), 32 k each
    const int w4  = tp >> 6;        // wave within cohort (0..3)
    const int fb2 = tp >> 5;        // phase-C batch (valid when tp<128: 0..3)
    const int unit = s * 32 + jj;
    const int bglob = grp * 8 + c * 4 + (fb2 & 3);
    float* sPc = sP + c * 2560;
    int* mycnt = barC + c;
    int* flgc  = flg + (grp * 2 + c) * 32;

    if (tid < 2) barC[tid] = 0;

    // W fragment: 32 float4 = k in [ks*32, ks*32+32) for unit jj
    const float4* Wg4 = (const float4*)Wg_l + (size_t)s * 8192;
    float4 wreg[32];
    #pragma unroll
    for (int kk = 0; kk < 32; ++kk)
        wreg[kk] = Wg4[(size_t)(ks * 32 + kk) * 32 + jj];

    float creg = 0.0f;
    if (tp < 128 && !first) creg = cbuf[(size_t)bglob * H_ + unit];

    __syncthreads();   // barC init + (LDS clean) — ONLY block-wide sync

    const float4* sH4 = (const float4*)sH;
    int seq = 0;

    for (int tt = 0; tt < TC_; ++tt) {
        const int t = t0 + tt;

        // xp prefetch (phase-C identity), gate-packed float4
        float4 xv = make_float4(0.f, 0.f, 0.f, 0.f);
        if (tp < 128)
            xv = *(const float4*)&xp[((size_t)bglob * TC_ + tt) * G_ + unit * 4];

        // ---- poll + gather own-cohort h(t-1) half into sH ----
        if (tt == 0) {
            if (first) {
                *(float4*)&sH[tp * 8 + c * 4] = make_float4(0.f, 0.f, 0.f, 0.f);
            } else {
                #pragma unroll
                for (int bb = 0; bb < 4; ++bb)
                    sH[tp * 8 + c * 4 + bb] =
                        hbuf[((size_t)(grp * 8 + c * 4 + bb) * T_ + (t0 - 1)) * H_ + tp];
            }
        } else {
            // every wave polls (lanes 0-7): no barrier needed before gather
            if ((tid & 63) < 8) {
                int* fp = flgc + (tid & 63);
                const int tgt = chkb + tt;
                while (__hip_atomic_load(fp, __ATOMIC_RELAXED, AG) < tgt)
                    __builtin_amdgcn_s_sleep(1);
            }
            const float* hsf = hx + (size_t)(((tt - 1) & 1) * 32 + grp) * 2048
                                  + (size_t)tp * 8 + c * 4;
            *(float4*)&sH[tp * 8 + c * 4] = ld_mall_16B(hsf);
        }
        cbar(mycnt, seq);   // sH half ready

        // ---- phase B: 32-k loop, W from registers, 4 batch accumulators ----
        float4 a0 = {0,0,0,0}, a1 = {0,0,0,0}, a2 = {0,0,0,0}, a3 = {0,0,0,0};
        #pragma unroll
        for (int kk = 0; kk < 32; ++kk) {
            const int k = ks * 32 + kk;
            const float4 wv = wreg[kk];
            const float4 hc = sH4[k * 2 + c];
            fma4(a0, hc.x, wv); fma4(a1, hc.y, wv);
            fma4(a2, hc.z, wv); fma4(a3, hc.w, wv);
        }
        red4(a0); red4(a1); red4(a2); red4(a3);   // sum ks pairs (lane ^ 32)
        if ((tid & 63) < 32) {
            float4* pp = (float4*)&sPc[(w4 * 32 + jj) * 20];
            pp[0] = a0; pp[1] = a1; pp[2] = a2; pp[3] = a3;
        }
        cbar(mycnt, seq);   // partials ready

        // ---- phase C: finish (tp < 128: 4 batches x 32 units) ----
        if (tp < 128) {
            float4 g4 = xv;
            #pragma unroll
            for (int w2 = 0; w2 < 4; ++w2) {
                const float4 pw = *(const float4*)&sPc[(w2 * 32 + jj) * 20 + fb2 * 4];
                g4.x += pw.x; g4.y += pw.y; g4.z += pw.z; g4.w += pw.w;
            }
            const float I = sigm(g4.x);
            const float F = sigm(g4.y);
            const float Gt = tanhf(g4.z);
            const float O = sigm(g4.w);
            creg = F * creg + I * Gt;
            const float hval = O * tanhf(creg);
            hbuf[((size_t)bglob * T_ + t) * H_ + unit] = hval;

            if (tt < TC_ - 1) {
                // paired publish: (fb2, fb2^1) share one u64 (lane ^ 32)
                const float hpart = __shfl_xor(hval, 32);
                if ((fb2 & 1) == 0) {
                    const unsigned long long pv =
                        ((unsigned long long)__float_as_uint(hpart) << 32)
                        | __float_as_uint(hval);
                    unsigned long long* dst = (unsigned long long*)
                        (hx + (size_t)((tt & 1) * 32 + grp) * 2048
                            + unit * 8 + c * 4 + fb2);
                    __hip_atomic_store(dst, pv, __ATOMIC_RELAXED, AG);
                }
            }
        }

        if (tt < TC_ - 1) {
            asm volatile("s_waitcnt vmcnt(0)" ::: "memory");  // per-wave drain
            cbar(mycnt, seq);   // all cohort publishes drained
            if (tp == 0)
                __hip_atomic_store(flgc + s, chkb + tt + 1, __ATOMIC_RELAXED, AG);
        }
    }

    if (tp < 128) cbuf[(size_t)bglob * H_ + unit] = creg;
}

// ---- final FC ----
extern "C" __global__ void __launch_bounds__(128)
fc_kernel(const float* __restrict__ hbuf, const float* __restrict__ fcw,
          const float* __restrict__ fcb, float* __restrict__ out) {
    __shared__ float wsm[256];
    const int tid = threadIdx.x;
    const int b = blockIdx.x;
    if (tid < 64) ((float4*)wsm)[tid] = ((const float4*)fcw)[tid];
    __syncthreads();
    if (tid < T_) {
        const float4* h4p = (const float4*)(hbuf + ((size_t)b * T_ + tid) * H_);
        const float4* w4p = (const float4*)wsm;
        float acc = fcb[0];
        #pragma unroll 8
        for (int k4 = 0; k4 < 64; ++k4) {
            float4 h4 = h4p[k4], w4 = w4p[k4];
            acc += h4.x * w4.x + h4.y * w4.y + h4.z * w4.z + h4.w * w4.w;
        }
        out[b * T_ + tid] = acc;
    }
}

extern "C" void kernel_launch(void* const* d_in, const int* in_sizes, int n_in,
                              void* d_out, int out_size, void* d_ws, size_t ws_size,
                              hipStream_t stream) {
    (void)in_sizes; (void)n_in; (void)out_size; (void)ws_size;
    const float* x    = (const float*)d_in[0];
    const float* Wih0 = (const float*)d_in[1];
    const float* Wihr = (const float*)d_in[2];
    const float* Whh  = (const float*)d_in[3];
    const float* bih  = (const float*)d_in[4];
    const float* bhh  = (const float*)d_in[5];
    const float* fcw  = (const float*)d_in[6];
    const float* fcb  = (const float*)d_in[7];
    float* out = (float*)d_out;
    float* ws  = (float*)d_ws;

    float* xp   = ws;
    float* hbuf = ws + XP_FLOATS;
    float* cbuf = hbuf + HBUF_FLOATS;
    float* wg   = cbuf + CBUF_FLOATS;
    float* hx   = wg + WG_FLOATS;
    int*   flg  = (int*)(ws + FLG_OFF_FLOATS);   // 64 lines x 32 ints

    hipMemsetAsync(flg, 0, 64 * 32 * sizeof(int), stream);
    hipLaunchKernelGGL(wt_kernel, dim3(WG_FLOATS / 256), dim3(256), 0, stream, Whh, wg);

    for (int l = 0; l < L_; ++l) {
        const int K = (l == 0) ? IN_ : H_;
        const float* src = (l == 0) ? x : hbuf;
        const float* Wih = (l == 0) ? Wih0 : (Wihr + (size_t)(l - 1) * G_ * H_);
        const float* Wg_l = wg + (size_t)l * (G_ * H_);
        for (int ch = 0; ch < NCH_; ++ch) {
            const int t0 = ch * TC_;
            const int chkb = (l * NCH_ + ch) * (TC_ - 1);
            hipLaunchKernelGGL(proj_kernel, dim3(1024), dim3(256), 0, stream,
                               src, Wih, bih + l * G_, bhh + l * G_, xp, K, t0);
            hipLaunchKernelGGL(rec10_kernel, dim3(256), dim3(512), 0, stream,
                               xp, Wg_l, hbuf, cbuf, hx, flg, t0, chkb, ch == 0 ? 1 : 0);
        }
    }
    hipLaunchKernelGGL(fc_kernel, dim3(B_), dim3(128), 0, stream, hbuf, fcw, fcb, out);
}

// Round 18
// 2473.415 us; speedup vs baseline: 1.1859x; 1.0025x over previous
//
#include <hip/hip_runtime.h>

#define B_ 256
#define T_ 80
#define IN_ 39
#define H_ 256
#define G_ 1024
#define L_ 5
#define TC_ 16
#define NCH_ 5

#define XP_FLOATS   (B_ * TC_ * G_)     // 4,194,304
#define HBUF_FLOATS (B_ * T_ * H_)      // 5,242,880
#define CBUF_FLOATS (B_ * H_)           // 65,536
#define WG_FLOATS   (L_ * G_ * H_)      // 1,310,720
#define HX_FLOATS   (2 * 32 * 2048)     // 131,072
#define FLG_OFF_FLOATS (XP_FLOATS + HBUF_FLOATS + CBUF_FLOATS + WG_FLOATS + HX_FLOATS)

#define AG __HIP_MEMORY_SCOPE_AGENT
#define WG __HIP_MEMORY_SCOPE_WORKGROUP

__device__ __forceinline__ float sigm(float x) { return 1.0f / (1.0f + expf(-x)); }
__device__ __forceinline__ void fma4(float4& a, float s, const float4& w) {
    a.x = fmaf(s, w.x, a.x); a.y = fmaf(s, w.y, a.y);
    a.z = fmaf(s, w.z, a.z); a.w = fmaf(s, w.w, a.w);
}
__device__ __forceinline__ void red4(float4& a) {
    a.x += __shfl_xor(a.x, 32); a.y += __shfl_xor(a.y, 32);
    a.z += __shfl_xor(a.z, 32); a.w += __shfl_xor(a.w, 32);
}

// MALL-coherent 16B load (sc0+sc1 = agent-atomic cache bits, 16B wide).
__device__ __forceinline__ float4 ld_mall_16B(const float* p) {
    float4 v;
    asm volatile("global_load_dwordx4 %0, %1, off sc0 sc1\n\t"
                 "s_waitcnt vmcnt(0)"
                 : "=&v"(v) : "v"(p) : "memory");
    return v;
}

// 4-wave cohort barrier: monotonic LDS counter.
__device__ __forceinline__ void cbar(int* cnt, int& seq) {
    seq += 4;
    asm volatile("s_waitcnt lgkmcnt(0)" ::: "memory");
    if ((threadIdx.x & 63) == 0)
        __hip_atomic_fetch_add(cnt, 1, __ATOMIC_RELAXED, WG);
    while (__hip_atomic_load(cnt, __ATOMIC_RELAXED, WG) < seq)
        __builtin_amdgcn_s_sleep(1);
    asm volatile("s_waitcnt lgkmcnt(0)" ::: "memory");
}

// ---- Wg: per-slice interleaved W_hh: Wg[l][s][k][j][g] = Whh[l][g*256+s*32+j][k] ----
extern "C" __global__ void __launch_bounds__(256)
wt_kernel(const float* __restrict__ Whh, float* __restrict__ Wg) {
    const int gid = blockIdx.x * 256 + threadIdx.x;
    const int g4 = gid & 3;
    const int j  = (gid >> 2) & 31;
    const int k  = (gid >> 7) & 255;
    const int s  = (gid >> 15) & 7;
    const int l  = gid >> 18;
    Wg[gid] = Whh[((size_t)(l * 1024 + g4 * 256 + s * 32 + j)) * 256 + k];
}

// ---- projection GEMM: 128x64 tile, 8x4 per thread, gate-packed xp ----
// Logical col c (0..63) = local unit*4+gate; W row r(c)=(c&3)*256+nt*16+(c>>2)
// (r15's proven permutation) -> epilogue stores one coalesced float4 per row.
extern "C" __global__ void __launch_bounds__(256)
proj_kernel(const float* __restrict__ src, const float* __restrict__ Wih,
            const float* __restrict__ bihl, const float* __restrict__ bhhl,
            float* __restrict__ xp, int K, int t0) {
    __shared__ float As[16 * 132];   // [kk][row 0..127]
    __shared__ float Bs[16 * 68];    // [kk][col 0..63]
    const int tid = threadIdx.x;
    const int mt = blockIdx.x >> 4, nt = blockIdx.x & 15;   // 32 x 16 tiles
    const int tx = tid & 15, ty = tid >> 4;
    const int lrA = tid >> 1, lc8 = (tid & 1) * 8;          // A loader
    const int lrB = tid >> 2, lc4 = (tid & 3) * 4;          // B loader

    const int ar = mt * 128 + lrA;
    const int ab = ar >> 4;
    const int at = t0 + (ar & 15);
    const float* arow = src + ((size_t)ab * T_ + at) * K;
    const int brow_idx = (lrB & 3) * 256 + nt * 16 + (lrB >> 2);   // permuted W row
    const float* brow = Wih + (size_t)brow_idx * K;

    float acc[8][4];
    #pragma unroll
    for (int i = 0; i < 8; ++i)
        #pragma unroll
        for (int j = 0; j < 4; ++j) acc[i][j] = 0.0f;

    for (int k0 = 0; k0 < K; k0 += 16) {
        __syncthreads();
        if (K == IN_) {
            #pragma unroll
            for (int i = 0; i < 8; ++i) {
                const int k = k0 + lc8 + i;
                As[(lc8 + i) * 132 + lrA] = (k < IN_) ? arow[k] : 0.0f;
            }
            #pragma unroll
            for (int i = 0; i < 4; ++i) {
                const int k = k0 + lc4 + i;
                Bs[(lc4 + i) * 68 + lrB] = (k < IN_) ? brow[k] : 0.0f;
            }
        } else {
            float4 a0 = *(const float4*)(arow + k0 + lc8);
            float4 a1 = *(const float4*)(arow + k0 + lc8 + 4);
            As[(lc8 + 0) * 132 + lrA] = a0.x;
            As[(lc8 + 1) * 132 + lrA] = a0.y;
            As[(lc8 + 2) * 132 + lrA] = a0.z;
            As[(lc8 + 3) * 132 + lrA] = a0.w;
            As[(lc8 + 4) * 132 + lrA] = a1.x;
            As[(lc8 + 5) * 132 + lrA] = a1.y;
            As[(lc8 + 6) * 132 + lrA] = a1.z;
            As[(lc8 + 7) * 132 + lrA] = a1.w;
            float4 bv = *(const float4*)(brow + k0 + lc4);
            Bs[(lc4 + 0) * 68 + lrB] = bv.x;
            Bs[(lc4 + 1) * 68 + lrB] = bv.y;
            Bs[(lc4 + 2) * 68 + lrB] = bv.z;
            Bs[(lc4 + 3) * 68 + lrB] = bv.w;
        }
        __syncthreads();
        #pragma unroll
        for (int kk = 0; kk < 16; ++kk) {
            const float4 aA = *(const float4*)&As[kk * 132 + ty * 8];
            const float4 aB = *(const float4*)&As[kk * 132 + ty * 8 + 4];
            const float4 b4 = *(const float4*)&Bs[kk * 68 + tx * 4];
            acc[0][0] += aA.x * b4.x; acc[0][1] += aA.x * b4.y;
            acc[0][2] += aA.x * b4.z; acc[0][3] += aA.x * b4.w;
            acc[1][0] += aA.y * b4.x; acc[1][1] += aA.y * b4.y;
            acc[1][2] += aA.y * b4.z; acc[1][3] += aA.y * b4.w;
            acc[2][0] += aA.z * b4.x; acc[2][1] += aA.z * b4.y;
            acc[2][2] += aA.z * b4.z; acc[2][3] += aA.z * b4.w;
            acc[3][0] += aA.w * b4.x; acc[3][1] += aA.w * b4.y;
            acc[3][2] += aA.w * b4.z; acc[3][3] += aA.w * b4.w;
            acc[4][0] += aB.x * b4.x; acc[4][1] += aB.x * b4.y;
            acc[4][2] += aB.x * b4.z; acc[4][3] += aB.x * b4.w;
            acc[5][0] += aB.y * b4.x; acc[5][1] += aB.y * b4.y;
            acc[5][2] += aB.y * b4.z; acc[5][3] += aB.y * b4.w;
            acc[6][0] += aB.z * b4.x; acc[6][1] += aB.z * b4.y;
            acc[6][2] += aB.z * b4.z; acc[6][3] += aB.z * b4.w;
            acc[7][0] += aB.w * b4.x; acc[7][1] += aB.w * b4.y;
            acc[7][2] += aB.w * b4.z; acc[7][3] += aB.w * b4.w;
        }
    }
    const int unit = nt * 16 + tx;
    const float bs0 = bihl[0 * 256 + unit] + bhhl[0 * 256 + unit];
    const float bs1 = bihl[1 * 256 + unit] + bhhl[1 * 256 + unit];
    const float bs2 = bihl[2 * 256 + unit] + bhhl[2 * 256 + unit];
    const float bs3 = bihl[3 * 256 + unit] + bhhl[3 * 256 + unit];
    #pragma unroll
    for (int i = 0; i < 8; ++i) {
        const int row = mt * 128 + ty * 8 + i;
        float4 o;
        o.x = acc[i][0] + bs0; o.y = acc[i][1] + bs1;
        o.z = acc[i][2] + bs2; o.w = acc[i][3] + bs3;
        *(float4*)&xp[(size_t)row * G_ + unit * 4] = o;   // coalesced, gate-packed
    }
}

// ---- recurrence: concurrent cohorts (r17, best measured) — UNCHANGED ----
extern "C" __global__ void __launch_bounds__(512, 2)
rec10_kernel(const float* __restrict__ xp, const float* __restrict__ Wg_l,
             float* __restrict__ hbuf, float* __restrict__ cbuf,
             float* __restrict__ hx, int* __restrict__ flg,
             int t0, int chkb, int first) {
    __shared__ float sH[2048];              // hT[k][fb] (8 KB), cohort halves
    __shared__ float sP[2 * 4 * 32 * 20];   // per-cohort part[w4][jj][20]
    __shared__ int   barC[2];

    const int tid = threadIdx.x;
    const int bid = blockIdx.x;
    const int grp = bid & 31;
    const int s   = bid >> 5;
    const int c   = tid >> 8;       // cohort 0/1
    const int tp  = tid & 255;      // index within cohort
    const int jj  = tp & 31;        // unit within slice
    const int ks  = tp >> 5;        // k-slice (0..7), 32 k each
    const int w4  = tp >> 6;        // wave within cohort (0..3)
    const int fb2 = tp >> 5;        // phase-C batch (valid when tp<128: 0..3)
    const int unit = s * 32 + jj;
    const int bglob = grp * 8 + c * 4 + (fb2 & 3);
    float* sPc = sP + c * 2560;
    int* mycnt = barC + c;
    int* flgc  = flg + (grp * 2 + c) * 32;

    if (tid < 2) barC[tid] = 0;

    const float4* Wg4 = (const float4*)Wg_l + (size_t)s * 8192;
    float4 wreg[32];
    #pragma unroll
    for (int kk = 0; kk < 32; ++kk)
        wreg[kk] = Wg4[(size_t)(ks * 32 + kk) * 32 + jj];

    float creg = 0.0f;
    if (tp < 128 && !first) creg = cbuf[(size_t)bglob * H_ + unit];

    __syncthreads();   // barC init — only block-wide sync

    const float4* sH4 = (const float4*)sH;
    int seq = 0;

    for (int tt = 0; tt < TC_; ++tt) {
        const int t = t0 + tt;

        float4 xv = make_float4(0.f, 0.f, 0.f, 0.f);
        if (tp < 128)
            xv = *(const float4*)&xp[((size_t)bglob * TC_ + tt) * G_ + unit * 4];

        if (tt == 0) {
            if (first) {
                *(float4*)&sH[tp * 8 + c * 4] = make_float4(0.f, 0.f, 0.f, 0.f);
            } else {
                #pragma unroll
                for (int bb = 0; bb < 4; ++bb)
                    sH[tp * 8 + c * 4 + bb] =
                        hbuf[((size_t)(grp * 8 + c * 4 + bb) * T_ + (t0 - 1)) * H_ + tp];
            }
        } else {
            if ((tid & 63) < 8) {
                int* fp = flgc + (tid & 63);
                const int tgt = chkb + tt;
                while (__hip_atomic_load(fp, __ATOMIC_RELAXED, AG) < tgt)
                    __builtin_amdgcn_s_sleep(1);
            }
            const float* hsf = hx + (size_t)(((tt - 1) & 1) * 32 + grp) * 2048
                                  + (size_t)tp * 8 + c * 4;
            *(float4*)&sH[tp * 8 + c * 4] = ld_mall_16B(hsf);
        }
        cbar(mycnt, seq);   // sH half ready

        float4 a0 = {0,0,0,0}, a1 = {0,0,0,0}, a2 = {0,0,0,0}, a3 = {0,0,0,0};
        #pragma unroll
        for (int kk = 0; kk < 32; ++kk) {
            const int k = ks * 32 + kk;
            const float4 wv = wreg[kk];
            const float4 hc = sH4[k * 2 + c];
            fma4(a0, hc.x, wv); fma4(a1, hc.y, wv);
            fma4(a2, hc.z, wv); fma4(a3, hc.w, wv);
        }
        red4(a0); red4(a1); red4(a2); red4(a3);
        if ((tid & 63) < 32) {
            float4* pp = (float4*)&sPc[(w4 * 32 + jj) * 20];
            pp[0] = a0; pp[1] = a1; pp[2] = a2; pp[3] = a3;
        }
        cbar(mycnt, seq);   // partials ready

        if (tp < 128) {
            float4 g4 = xv;
            #pragma unroll
            for (int w2 = 0; w2 < 4; ++w2) {
                const float4 pw = *(const float4*)&sPc[(w2 * 32 + jj) * 20 + fb2 * 4];
                g4.x += pw.x; g4.y += pw.y; g4.z += pw.z; g4.w += pw.w;
            }
            const float I = sigm(g4.x);
            const float F = sigm(g4.y);
            const float Gt = tanhf(g4.z);
            const float O = sigm(g4.w);
            creg = F * creg + I * Gt;
            const float hval = O * tanhf(creg);
            hbuf[((size_t)bglob * T_ + t) * H_ + unit] = hval;

            if (tt < TC_ - 1) {
                const float hpart = __shfl_xor(hval, 32);
                if ((fb2 & 1) == 0) {
                    const unsigned long long pv =
                        ((unsigned long long)__float_as_uint(hpart) << 32)
                        | __float_as_uint(hval);
                    unsigned long long* dst = (unsigned long long*)
                        (hx + (size_t)((tt & 1) * 32 + grp) * 2048
                            + unit * 8 + c * 4 + fb2);
                    __hip_atomic_store(dst, pv, __ATOMIC_RELAXED, AG);
                }
            }
        }

        if (tt < TC_ - 1) {
            asm volatile("s_waitcnt vmcnt(0)" ::: "memory");
            cbar(mycnt, seq);   // all cohort publishes drained
            if (tp == 0)
                __hip_atomic_store(flgc + s, chkb + tt + 1, __ATOMIC_RELAXED, AG);
        }
    }

    if (tp < 128) cbuf[(size_t)bglob * H_ + unit] = creg;
}

// ---- final FC ----
extern "C" __global__ void __launch_bounds__(128)
fc_kernel(const float* __restrict__ hbuf, const float* __restrict__ fcw,
          const float* __restrict__ fcb, float* __restrict__ out) {
    __shared__ float wsm[256];
    const int tid = threadIdx.x;
    const int b = blockIdx.x;
    if (tid < 64) ((float4*)wsm)[tid] = ((const float4*)fcw)[tid];
    __syncthreads();
    if (tid < T_) {
        const float4* h4p = (const float4*)(hbuf + ((size_t)b * T_ + tid) * H_);
        const float4* w4p = (const float4*)wsm;
        float acc = fcb[0];
        #pragma unroll 8
        for (int k4 = 0; k4 < 64; ++k4) {
            float4 h4 = h4p[k4], w4 = w4p[k4];
            acc += h4.x * w4.x + h4.y * w4.y + h4.z * w4.z + h4.w * w4.w;
        }
        out[b * T_ + tid] = acc;
    }
}

extern "C" void kernel_launch(void* const* d_in, const int* in_sizes, int n_in,
                              void* d_out, int out_size, void* d_ws, size_t ws_size,
                              hipStream_t stream) {
    (void)in_sizes; (void)n_in; (void)out_size; (void)ws_size;
    const float* x    = (const float*)d_in[0];
    const float* Wih0 = (const float*)d_in[1];
    const float* Wihr = (const float*)d_in[2];
    const float* Whh  = (const float*)d_in[3];
    const float* bih  = (const float*)d_in[4];
    const float* bhh  = (const float*)d_in[5];
    const float* fcw  = (const float*)d_in[6];
    const float* fcb  = (const float*)d_in[7];
    float* out = (float*)d_out;
    float* ws  = (float*)d_ws;

    float* xp   = ws;
    float* hbuf = ws + XP_FLOATS;
    float* cbuf = hbuf + HBUF_FLOATS;
    float* wg   = cbuf + CBUF_FLOATS;
    float* hx   = wg + WG_FLOATS;
    int*   flg  = (int*)(ws + FLG_OFF_FLOATS);   // 64 lines x 32 ints

    hipMemsetAsync(flg, 0, 64 * 32 * sizeof(int), stream);
    hipLaunchKernelGGL(wt_kernel, dim3(WG_FLOATS / 256), dim3(256), 0, stream, Whh, wg);

    for (int l = 0; l < L_; ++l) {
        const int K = (l == 0) ? IN_ : H_;
        const float* src = (l == 0) ? x : hbuf;
        const float* Wih = (l == 0) ? Wih0 : (Wihr + (size_t)(l - 1) * G_ * H_);
        const float* Wg_l = wg + (size_t)l * (G_ * H_);
        for (int ch = 0; ch < NCH_; ++ch) {
            const int t0 = ch * TC_;
            const int chkb = (l * NCH_ + ch) * (TC_ - 1);
            hipLaunchKernelGGL(proj_kernel, dim3(512), dim3(256), 0, stream,
                               src, Wih, bih + l * G_, bhh + l * G_, xp, K, t0);
            hipLaunchKernelGGL(rec10_kernel, dim3(256), dim3(512), 0, stream,
                               xp, Wg_l, hbuf, cbuf, hx, flg, t0, chkb, ch == 0 ? 1 : 0);
        }
    }
    hipLaunchKernelGGL(fc_kernel, dim3(B_), dim3(128), 0, stream, hbuf, fcw, fcb, out);
}

// Round 19
// 2169.914 us; speedup vs baseline: 1.3518x; 1.1399x over previous
//
#include <hip/hip_runtime.h>

#define B_ 256
#define T_ 80
#define IN_ 39
#define H_ 256
#define G_ 1024
#define L_ 5
#define TC_ 16
#define NCH_ 5

#define XP_FLOATS   (B_ * TC_ * G_)     // 4,194,304
#define HBUF_FLOATS (B_ * T_ * H_)      // 5,242,880
#define CBUF_FLOATS (B_ * H_)           // 65,536
#define WG_FLOATS   (L_ * G_ * H_)      // 1,310,720
#define HX_FLOATS   (2 * 32 * 2048)     // 131,072
#define FLG_INTS_L  2048                // per-layer flag ints (64 lines x 32)

#define AG __HIP_MEMORY_SCOPE_AGENT
#define WGS __HIP_MEMORY_SCOPE_WORKGROUP

__device__ __forceinline__ float sigm(float x) { return 1.0f / (1.0f + expf(-x)); }
__device__ __forceinline__ void fma4(float4& a, float s, const float4& w) {
    a.x = fmaf(s, w.x, a.x); a.y = fmaf(s, w.y, a.y);
    a.z = fmaf(s, w.z, a.z); a.w = fmaf(s, w.w, a.w);
}
__device__ __forceinline__ void red4(float4& a) {
    a.x += __shfl_xor(a.x, 32); a.y += __shfl_xor(a.y, 32);
    a.z += __shfl_xor(a.z, 32); a.w += __shfl_xor(a.w, 32);
}

// MALL-coherent 16B load (sc0+sc1 = agent-atomic cache bits, 16B wide).
__device__ __forceinline__ float4 ld_mall_16B(const float* p) {
    float4 v;
    asm volatile("global_load_dwordx4 %0, %1, off sc0 sc1\n\t"
                 "s_waitcnt vmcnt(0)"
                 : "=&v"(v) : "v"(p) : "memory");
    return v;
}

// 4-wave cohort barrier: monotonic LDS counter.
__device__ __forceinline__ void cbar(int* cnt, int& seq) {
    seq += 4;
    asm volatile("s_waitcnt lgkmcnt(0)" ::: "memory");
    if ((threadIdx.x & 63) == 0)
        __hip_atomic_fetch_add(cnt, 1, __ATOMIC_RELAXED, WGS);
    while (__hip_atomic_load(cnt, __ATOMIC_RELAXED, WGS) < seq)
        __builtin_amdgcn_s_sleep(1);
    asm volatile("s_waitcnt lgkmcnt(0)" ::: "memory");
}

// ---- Wg: per-slice interleaved W_hh: Wg[l][s][k][j][g] = Whh[l][g*256+s*32+j][k] ----
extern "C" __global__ void __launch_bounds__(256)
wt_kernel(const float* __restrict__ Whh, float* __restrict__ Wg) {
    const int gid = blockIdx.x * 256 + threadIdx.x;
    const int g4 = gid & 3;
    const int j  = (gid >> 2) & 31;
    const int k  = (gid >> 7) & 255;
    const int s  = (gid >> 15) & 7;
    const int l  = gid >> 18;
    Wg[gid] = Whh[((size_t)(l * 1024 + g4 * 256 + s * 32 + j)) * 256 + k];
}

// ---- projection GEMM (multi-task): 128x64 tile, 8x4/thread, gate-packed xp ----
// Task = blockIdx.x>>9; l = lmin+task; ch = d-l. xp_l = xp_base + l*xp_s.
extern "C" __global__ void __launch_bounds__(256)
proj_multi(const float* __restrict__ x, const float* __restrict__ Wih0,
           const float* __restrict__ Wihr,
           const float* __restrict__ bih, const float* __restrict__ bhh,
           const float* __restrict__ hbuf,
           float* __restrict__ xp_base, unsigned long long xp_s,
           int d, int lmin) {
    __shared__ float As[16 * 132];
    __shared__ float Bs[16 * 68];
    const int task = blockIdx.x >> 9;
    const int l = lmin + task;
    const int ch = d - l;
    const int t0 = ch * TC_;
    const int K = (l == 0) ? IN_ : H_;
    const float* src = (l == 0) ? x : hbuf;
    const float* Wih = (l == 0) ? Wih0 : (Wihr + (size_t)(l - 1) * G_ * H_);
    const float* bihl = bih + l * G_;
    const float* bhhl = bhh + l * G_;
    float* xp = xp_base + (size_t)l * xp_s;

    const int bid9 = blockIdx.x & 511;
    const int tid = threadIdx.x;
    const int mt = bid9 >> 4, nt = bid9 & 15;
    const int tx = tid & 15, ty = tid >> 4;
    const int lrA = tid >> 1, lc8 = (tid & 1) * 8;
    const int lrB = tid >> 2, lc4 = (tid & 3) * 4;

    const int ar = mt * 128 + lrA;
    const int ab = ar >> 4;
    const int at = t0 + (ar & 15);
    const float* arow = src + ((size_t)ab * T_ + at) * K;
    const int brow_idx = (lrB & 3) * 256 + nt * 16 + (lrB >> 2);
    const float* brow = Wih + (size_t)brow_idx * K;

    float acc[8][4];
    #pragma unroll
    for (int i = 0; i < 8; ++i)
        #pragma unroll
        for (int j = 0; j < 4; ++j) acc[i][j] = 0.0f;

    for (int k0 = 0; k0 < K; k0 += 16) {
        __syncthreads();
        if (K == IN_) {
            #pragma unroll
            for (int i = 0; i < 8; ++i) {
                const int k = k0 + lc8 + i;
                As[(lc8 + i) * 132 + lrA] = (k < IN_) ? arow[k] : 0.0f;
            }
            #pragma unroll
            for (int i = 0; i < 4; ++i) {
                const int k = k0 + lc4 + i;
                Bs[(lc4 + i) * 68 + lrB] = (k < IN_) ? brow[k] : 0.0f;
            }
        } else {
            float4 a0 = *(const float4*)(arow + k0 + lc8);
            float4 a1 = *(const float4*)(arow + k0 + lc8 + 4);
            As[(lc8 + 0) * 132 + lrA] = a0.x;
            As[(lc8 + 1) * 132 + lrA] = a0.y;
            As[(lc8 + 2) * 132 + lrA] = a0.z;
            As[(lc8 + 3) * 132 + lrA] = a0.w;
            As[(lc8 + 4) * 132 + lrA] = a1.x;
            As[(lc8 + 5) * 132 + lrA] = a1.y;
            As[(lc8 + 6) * 132 + lrA] = a1.z;
            As[(lc8 + 7) * 132 + lrA] = a1.w;
            float4 bv = *(const float4*)(brow + k0 + lc4);
            Bs[(lc4 + 0) * 68 + lrB] = bv.x;
            Bs[(lc4 + 1) * 68 + lrB] = bv.y;
            Bs[(lc4 + 2) * 68 + lrB] = bv.z;
            Bs[(lc4 + 3) * 68 + lrB] = bv.w;
        }
        __syncthreads();
        #pragma unroll
        for (int kk = 0; kk < 16; ++kk) {
            const float4 aA = *(const float4*)&As[kk * 132 + ty * 8];
            const float4 aB = *(const float4*)&As[kk * 132 + ty * 8 + 4];
            const float4 b4 = *(const float4*)&Bs[kk * 68 + tx * 4];
            acc[0][0] += aA.x * b4.x; acc[0][1] += aA.x * b4.y;
            acc[0][2] += aA.x * b4.z; acc[0][3] += aA.x * b4.w;
            acc[1][0] += aA.y * b4.x; acc[1][1] += aA.y * b4.y;
            acc[1][2] += aA.y * b4.z; acc[1][3] += aA.y * b4.w;
            acc[2][0] += aA.z * b4.x; acc[2][1] += aA.z * b4.y;
            acc[2][2] += aA.z * b4.z; acc[2][3] += aA.z * b4.w;
            acc[3][0] += aA.w * b4.x; acc[3][1] += aA.w * b4.y;
            acc[3][2] += aA.w * b4.z; acc[3][3] += aA.w * b4.w;
            acc[4][0] += aB.x * b4.x; acc[4][1] += aB.x * b4.y;
            acc[4][2] += aB.x * b4.z; acc[4][3] += aB.x * b4.w;
            acc[5][0] += aB.y * b4.x; acc[5][1] += aB.y * b4.y;
            acc[5][2] += aB.y * b4.z; acc[5][3] += aB.y * b4.w;
            acc[6][0] += aB.z * b4.x; acc[6][1] += aB.z * b4.y;
            acc[6][2] += aB.z * b4.z; acc[6][3] += aB.z * b4.w;
            acc[7][0] += aB.w * b4.x; acc[7][1] += aB.w * b4.y;
            acc[7][2] += aB.w * b4.z; acc[7][3] += aB.w * b4.w;
        }
    }
    const int unit = nt * 16 + tx;
    const float bs0 = bihl[0 * 256 + unit] + bhhl[0 * 256 + unit];
    const float bs1 = bihl[1 * 256 + unit] + bhhl[1 * 256 + unit];
    const float bs2 = bihl[2 * 256 + unit] + bhhl[2 * 256 + unit];
    const float bs3 = bihl[3 * 256 + unit] + bhhl[3 * 256 + unit];
    #pragma unroll
    for (int i = 0; i < 8; ++i) {
        const int row = mt * 128 + ty * 8 + i;
        float4 o;
        o.x = acc[i][0] + bs0; o.y = acc[i][1] + bs1;
        o.z = acc[i][2] + bs2; o.w = acc[i][3] + bs3;
        *(float4*)&xp[(size_t)row * G_ + unit * 4] = o;
    }
}

// ---- recurrence (multi-task): r17 concurrent cohorts + full-16 hx handoff ----
// Task = blockIdx.x>>8; groups 8-CONTIGUOUS in bid (co-residency safety).
// All 16 steps publish+flag (chkb = q*16); tt==0 (!first) polls >= chkb and
// gathers parity (tt+1)&1 — removes the hbuf t0-gather (which would race with
// same-slot task (l+1,ch-1) in wavefront mode).
extern "C" __global__ void __launch_bounds__(512, 2)
rec_multi(const float* __restrict__ xp_base, unsigned long long xp_s,
          const float* __restrict__ wg, float* __restrict__ hbuf,
          float* __restrict__ cbuf_base, unsigned long long cb_s,
          float* __restrict__ hx_base, unsigned long long hx_s,
          int* __restrict__ flg_base, unsigned long long flg_s,
          int d, int lmin) {
    __shared__ float sH[2048];
    __shared__ float sP[2 * 4 * 32 * 20];
    __shared__ int   barC[2];

    const int tid = threadIdx.x;
    const int task = blockIdx.x >> 8;
    const int l = lmin + task;
    const int ch = d - l;
    const int b8 = blockIdx.x & 255;
    const int grp = b8 >> 3;          // 8-contiguous groups
    const int s   = b8 & 7;
    const int t0 = ch * TC_;
    const int chkb = (l * NCH_ + ch) * TC_;
    const int first = (ch == 0);

    const float* xp = xp_base + (size_t)l * xp_s;
    const float* Wg_l = wg + (size_t)l * (G_ * H_);
    float* cbuf = cbuf_base + (size_t)l * cb_s;
    float* hx = hx_base + (size_t)l * hx_s;
    int* flg = flg_base + (size_t)l * flg_s;

    const int c = tid >> 8;
    const int tp = tid & 255;
    const int jj = tp & 31;
    const int ks = tp >> 5;
    const int w4 = tp >> 6;
    const int fb2 = tp >> 5;          // phase-C batch (tp<128: 0..3)
    const int unit = s * 32 + jj;
    const int bglob = grp * 8 + c * 4 + (fb2 & 3);
    float* sPc = sP + c * 2560;
    int* mycnt = barC + c;
    int* flgc = flg + (grp * 2 + c) * 32;

    if (tid < 2) barC[tid] = 0;

    const float4* Wg4 = (const float4*)Wg_l + (size_t)s * 8192;
    float4 wreg[32];
    #pragma unroll
    for (int kk = 0; kk < 32; ++kk)
        wreg[kk] = Wg4[(size_t)(ks * 32 + kk) * 32 + jj];

    float creg = 0.0f;
    if (tp < 128 && !first) creg = cbuf[(size_t)bglob * H_ + unit];

    __syncthreads();   // barC init — only block-wide sync

    const float4* sH4 = (const float4*)sH;
    int seq = 0;

    for (int tt = 0; tt < TC_; ++tt) {
        const int t = t0 + tt;

        float4 xv = make_float4(0.f, 0.f, 0.f, 0.f);
        if (tp < 128)
            xv = *(const float4*)&xp[((size_t)bglob * TC_ + tt) * G_ + unit * 4];

        if (tt == 0 && first) {
            *(float4*)&sH[tp * 8 + c * 4] = make_float4(0.f, 0.f, 0.f, 0.f);
        } else {
            if ((tid & 63) < 8) {
                int* fp = flgc + (tid & 63);
                const int tgt = chkb + tt;   // tt==0: prev chunk's final value
                while (__hip_atomic_load(fp, __ATOMIC_RELAXED, AG) < tgt)
                    __builtin_amdgcn_s_sleep(1);
            }
            const float* hsf = hx + (size_t)((((tt + 1) & 1)) * 32 + grp) * 2048
                                  + (size_t)tp * 8 + c * 4;
            *(float4*)&sH[tp * 8 + c * 4] = ld_mall_16B(hsf);
        }
        cbar(mycnt, seq);   // sH half ready

        float4 a0 = {0,0,0,0}, a1 = {0,0,0,0}, a2 = {0,0,0,0}, a3 = {0,0,0,0};
        #pragma unroll
        for (int kk = 0; kk < 32; ++kk) {
            const int k = ks * 32 + kk;
            const float4 wv = wreg[kk];
            const float4 hc = sH4[k * 2 + c];
            fma4(a0, hc.x, wv); fma4(a1, hc.y, wv);
            fma4(a2, hc.z, wv); fma4(a3, hc.w, wv);
        }
        red4(a0); red4(a1); red4(a2); red4(a3);
        if ((tid & 63) < 32) {
            float4* pp = (float4*)&sPc[(w4 * 32 + jj) * 20];
            pp[0] = a0; pp[1] = a1; pp[2] = a2; pp[3] = a3;
        }
        cbar(mycnt, seq);   // partials ready

        if (tp < 128) {
            float4 g4 = xv;
            #pragma unroll
            for (int w2 = 0; w2 < 4; ++w2) {
                const float4 pw = *(const float4*)&sPc[(w2 * 32 + jj) * 20 + fb2 * 4];
                g4.x += pw.x; g4.y += pw.y; g4.z += pw.z; g4.w += pw.w;
            }
            const float I = sigm(g4.x);
            const float F = sigm(g4.y);
            const float Gt = tanhf(g4.z);
            const float O = sigm(g4.w);
            creg = F * creg + I * Gt;
            const float hval = O * tanhf(creg);
            hbuf[((size_t)bglob * T_ + t) * H_ + unit] = hval;

            // publish EVERY step (parity tt&1)
            const float hpart = __shfl_xor(hval, 32);
            if ((fb2 & 1) == 0) {
                const unsigned long long pv =
                    ((unsigned long long)__float_as_uint(hpart) << 32)
                    | __float_as_uint(hval);
                unsigned long long* dst = (unsigned long long*)
                    (hx + (size_t)((tt & 1) * 32 + grp) * 2048
                        + unit * 8 + c * 4 + fb2);
                __hip_atomic_store(dst, pv, __ATOMIC_RELAXED, AG);
            }
        }

        asm volatile("s_waitcnt vmcnt(0)" ::: "memory");
        cbar(mycnt, seq);   // all cohort publishes drained
        if (tp == 0)
            __hip_atomic_store(flgc + s, chkb + tt + 1, __ATOMIC_RELAXED, AG);
    }

    if (tp < 128) cbuf[(size_t)bglob * H_ + unit] = creg;
}

// ---- final FC ----
extern "C" __global__ void __launch_bounds__(128)
fc_kernel(const float* __restrict__ hbuf, const float* __restrict__ fcw,
          const float* __restrict__ fcb, float* __restrict__ out) {
    __shared__ float wsm[256];
    const int tid = threadIdx.x;
    const int b = blockIdx.x;
    if (tid < 64) ((float4*)wsm)[tid] = ((const float4*)fcw)[tid];
    __syncthreads();
    if (tid < T_) {
        const float4* h4p = (const float4*)(hbuf + ((size_t)b * T_ + tid) * H_);
        const float4* w4p = (const float4*)wsm;
        float acc = fcb[0];
        #pragma unroll 8
        for (int k4 = 0; k4 < 64; ++k4) {
            float4 h4 = h4p[k4], w4 = w4p[k4];
            acc += h4.x * w4.x + h4.y * w4.y + h4.z * w4.z + h4.w * w4.w;
        }
        out[b * T_ + tid] = acc;
    }
}

extern "C" void kernel_launch(void* const* d_in, const int* in_sizes, int n_in,
                              void* d_out, int out_size, void* d_ws, size_t ws_size,
                              hipStream_t stream) {
    (void)in_sizes; (void)n_in; (void)out_size;
    const float* x    = (const float*)d_in[0];
    const float* Wih0 = (const float*)d_in[1];
    const float* Wihr = (const float*)d_in[2];
    const float* Whh  = (const float*)d_in[3];
    const float* bih  = (const float*)d_in[4];
    const float* bhh  = (const float*)d_in[5];
    const float* fcw  = (const float*)d_in[6];
    const float* fcb  = (const float*)d_in[7];
    float* out = (float*)d_out;
    float* ws  = (float*)d_ws;

    // wavefront needs per-layer xp/cbuf/hx/flg (~114.1 MB); else serial fallback
    const size_t WF_ELEMS = (size_t)5 * XP_FLOATS + HBUF_FLOATS
                          + (size_t)5 * CBUF_FLOATS + WG_FLOATS
                          + (size_t)5 * HX_FLOATS + (size_t)5 * FLG_INTS_L;
    const int wf = (ws_size >= WF_ELEMS * 4) ? 1 : 0;

    const unsigned long long xp_s  = wf ? XP_FLOATS   : 0;
    const unsigned long long cb_s  = wf ? CBUF_FLOATS : 0;
    const unsigned long long hx_s  = wf ? HX_FLOATS   : 0;
    const unsigned long long flg_s = wf ? FLG_INTS_L  : 0;
    const int nrep = wf ? 5 : 1;

    float* xp   = ws;
    float* hbuf = xp + (size_t)nrep * XP_FLOATS;
    float* cbuf = hbuf + HBUF_FLOATS;
    float* wg   = cbuf + (size_t)nrep * CBUF_FLOATS;
    float* hx   = wg + WG_FLOATS;
    int*   flg  = (int*)(hx + (size_t)nrep * HX_FLOATS);

    hipMemsetAsync(flg, 0, (size_t)nrep * FLG_INTS_L * sizeof(int), stream);
    hipLaunchKernelGGL(wt_kernel, dim3(WG_FLOATS / 256), dim3(256), 0, stream, Whh, wg);

    if (wf) {
        for (int dd = 0; dd <= L_ + NCH_ - 2; ++dd) {
            const int lmin = (dd - (NCH_ - 1) > 0) ? (dd - (NCH_ - 1)) : 0;
            const int lmax = (dd < L_ - 1) ? dd : (L_ - 1);
            const int n = lmax - lmin + 1;
            hipLaunchKernelGGL(proj_multi, dim3(n * 512), dim3(256), 0, stream,
                               x, Wih0, Wihr, bih, bhh, hbuf, xp, xp_s, dd, lmin);
            hipLaunchKernelGGL(rec_multi, dim3(n * 256), dim3(512), 0, stream,
                               xp, xp_s, wg, hbuf, cbuf, cb_s, hx, hx_s,
                               flg, flg_s, dd, lmin);
        }
    } else {
        for (int l = 0; l < L_; ++l) {
            for (int ch = 0; ch < NCH_; ++ch) {
                const int dd = l + ch;   // lmin=l -> task0 = (l, ch)
                hipLaunchKernelGGL(proj_multi, dim3(512), dim3(256), 0, stream,
                                   x, Wih0, Wihr, bih, bhh, hbuf, xp, xp_s, dd, l);
                hipLaunchKernelGGL(rec_multi, dim3(256), dim3(512), 0, stream,
                                   xp, xp_s, wg, hbuf, cbuf, cb_s, hx, hx_s,
                                   flg, flg_s, dd, l);
            }
        }
    }
    hipLaunchKernelGGL(fc_kernel, dim3(B_), dim3(128), 0, stream, hbuf, fcw, fcb, out);
}